// Round 8
// baseline (559.647 us; speedup 1.0000x reference)
//
#include <hip/hip_runtime.h>
#include <hip/hip_cooperative_groups.h>

namespace cg = cooperative_groups;

// Problem constants
#define TD 128        // D
#define TS 1024       // SIZE
#define TT 2048       // T
#define NROWS 32768   // B*T
#define EMA_W 0.99f

// d_out layout (flat fp32): [quantized BxDxT][diff][new_embedding SxD][new_usage S]
#define OFF_Q     0
#define OFF_DIFF  4194304
#define OFF_EMB   4194305
#define OFF_USAGE 4325377

// ws layout (words). End = 4,591,684 w = 18.37 MB < 19.15 MB (R7-proven) < 19.68 MB (R4-proven)
#define WS_E2      0         // 1024 f
#define WS_COUNTS  1024      // 1024 f
#define WS_CODES   2048      // 32768 i
#define WS_ROWLIST 34816     // 32768 i
#define WS_OFFS    67584     // 1025 i
#define WS_CURSOR  68612     // 1024 i
#define WS_DIFFACC 69636     // 64 f
#define WS_PACKED  69700     // 32768 u64 = 65536 w (byte off 278800 %8==0)
#define WS_EHI     135236    // 65536 w (byte 540944 %16==0)
#define WS_ELO     200772    // 65536 w
#define WS_PART    266308    // 131072 w
#define WS_XHI     397380    // 2097152 w (byte 1589520 %16==0)
#define WS_XLO     2494532   // 2097152 w -> end 4591684

typedef _Float16 f16x8 __attribute__((ext_vector_type(8)));
typedef _Float16 half4 __attribute__((ext_vector_type(4)));
typedef float    f32x4 __attribute__((ext_vector_type(4)));

__device__ __forceinline__ unsigned int ford(float s) {
    unsigned int u = __float_as_uint(s);
    return (u & 0x80000000u) ? ~u : (u | 0x80000000u);
}

// ================= phase bodies (shared by mega + fallback) =================

__device__ void phase_prep(const float* __restrict__ x, const float* __restrict__ emb,
                           _Float16* __restrict__ xhi, _Float16* __restrict__ xlo,
                           _Float16* __restrict__ ehi, _Float16* __restrict__ elo,
                           float* __restrict__ e2, float* __restrict__ part,
                           float* __restrict__ counts, float* __restrict__ diffacc,
                           unsigned long long* __restrict__ packed, char* smbuf) {
    const int tid = threadIdx.x, bid = blockIdx.x, G = gridDim.x;
    const int lane = tid & 63, wid = tid >> 6;
    // job A: x [B][D][T] -> xhi/xlo [N][D] (LDS transpose + f16 hi/lo split)
    {
        float (*xs)[132] = (float(*)[132])smbuf;
        const float4* x4 = (const float4*)x;
        for (int u = bid; u < 512; u += G) {
            const int b = u >> 5, tc = u & 31;
            #pragma unroll
            for (int p = 0; p < 8; p++) {
                int idx = p * 256 + tid;
                int d = idx >> 4, t4 = idx & 15;
                float4 v = x4[((size_t)b * TD + d) * 512 + tc * 16 + t4];
                xs[t4 * 4 + 0][d] = v.x;
                xs[t4 * 4 + 1][d] = v.y;
                xs[t4 * 4 + 2][d] = v.z;
                xs[t4 * 4 + 3][d] = v.w;
            }
            __syncthreads();
            const int ld = tid & 31;
            #pragma unroll
            for (int p = 0; p < 8; p++) {
                int tl = p * 8 + (tid >> 5);
                float4 v = *(const float4*)&xs[tl][ld * 4];
                half4 h, l;
                h[0] = (_Float16)v.x; l[0] = (_Float16)(v.x - (float)h[0]);
                h[1] = (_Float16)v.y; l[1] = (_Float16)(v.y - (float)h[1]);
                h[2] = (_Float16)v.z; l[2] = (_Float16)(v.z - (float)h[2]);
                h[3] = (_Float16)v.w; l[3] = (_Float16)(v.w - (float)h[3]);
                size_t n = (size_t)b * TT + tc * 64 + tl;
                *(half4*)(xhi + n * TD + ld * 4) = h;
                *(half4*)(xlo + n * TD + ld * 4) = l;
            }
            __syncthreads();
        }
    }
    // job B: emb split + e2 + part zero (one wave per code row)
    {
        const int gw = bid * 4 + wid, nw = G * 4;
        for (int s = gw; s < TS; s += nw) {
            size_t base = (size_t)s * TD;
            float v0 = emb[base + lane], v1 = emb[base + 64 + lane];
            _Float16 h0 = (_Float16)v0, h1 = (_Float16)v1;
            ehi[base + lane] = h0;      elo[base + lane] = (_Float16)(v0 - (float)h0);
            ehi[base + 64 + lane] = h1; elo[base + 64 + lane] = (_Float16)(v1 - (float)h1);
            part[base + lane] = 0.f;    part[base + 64 + lane] = 0.f;
            float sq = v0 * v0 + v1 * v1;
            #pragma unroll
            for (int off = 32; off; off >>= 1) sq += __shfl_down(sq, off, 64);
            if (lane == 0) e2[s] = sq;
        }
    }
    // job C: init packed / zero counts / diffacc
    const int gt = bid * 256 + tid, gs = G * 256;
    for (int i = gt; i < NROWS; i += gs) packed[i] = ~0ull;
    for (int i = gt; i < TS; i += gs) counts[i] = 0.f;
    if (gt < 64) diffacc[gt] = 0.f;
}

// dist: wave-unit = 16 rows x 256 codes; 8192 units; fr=1 keeps VGPR ~100.
// 16x16x32 MFMA, R4/R6/R7-verified maps; argmin merged via packed u64 atomicMin.
__device__ void phase_dist(const _Float16* __restrict__ xhi, const _Float16* __restrict__ xlo,
                           const _Float16* __restrict__ ehi, const _Float16* __restrict__ elo,
                           const float* __restrict__ e2,
                           unsigned long long* __restrict__ packed) {
    const int tid = threadIdx.x, lane = tid & 63;
    const int l15 = lane & 15, lk = lane >> 4;
    const int nw = gridDim.x * 4;
    for (int u = blockIdx.x * 4 + (tid >> 6); u < 8192; u += nw) {
        const int rf = u & 2047, cq = u >> 11;
        const int r0 = rf * 16, cb = cq * 256;
        // A frags: row = lane&15, k = (lane>>4)*8 + j
        f16x8 ahi[4], alo[4];
        const size_t ab = (size_t)(r0 + l15) * TD + lk * 8;
        #pragma unroll
        for (int ks = 0; ks < 4; ks++) {
            ahi[ks] = *(const f16x8*)(xhi + ab + ks * 32);
            alo[ks] = *(const f16x8*)(xlo + ab + ks * 32);
        }
        float bestV[4]; int bestI[4];
        #pragma unroll
        for (int i = 0; i < 4; i++) { bestV[i] = 3.4e38f; bestI[i] = 0; }
        for (int ct = 0; ct < 16; ct++) {
            const int c0 = cb + ct * 16;
            const size_t bb = (size_t)(c0 + l15) * TD + lk * 8;
            f16x8 bh[4], bl[4];
            #pragma unroll
            for (int ks = 0; ks < 4; ks++) {
                bh[ks] = *(const f16x8*)(ehi + bb + ks * 32);
                bl[ks] = *(const f16x8*)(elo + bb + ks * 32);
            }
            f32x4 acc = (f32x4){0.f, 0.f, 0.f, 0.f};
            #pragma unroll
            for (int ks = 0; ks < 4; ks++) {
                acc = __builtin_amdgcn_mfma_f32_16x16x32_f16(ahi[ks], bh[ks], acc, 0, 0, 0);
                acc = __builtin_amdgcn_mfma_f32_16x16x32_f16(ahi[ks], bl[ks], acc, 0, 0, 0);
                acc = __builtin_amdgcn_mfma_f32_16x16x32_f16(alo[ks], bh[ks], acc, 0, 0, 0);
            }
            float ev = e2[c0 + l15];
            #pragma unroll
            for (int i = 0; i < 4; i++) {   // C/D: col=lane&15, row=lk*4+i
                float sc = fmaf(-2.f, acc[i], ev);
                if (sc < bestV[i]) { bestV[i] = sc; bestI[i] = c0 + l15; }
            }
        }
        #pragma unroll
        for (int sl = 0; sl < 4; sl++) {
            #pragma unroll
            for (int m = 8; m >= 1; m >>= 1) {
                float ov = __shfl_xor(bestV[sl], m, 64);
                int   oi = __shfl_xor(bestI[sl], m, 64);
                if (ov < bestV[sl] || (ov == bestV[sl] && oi < bestI[sl])) {
                    bestV[sl] = ov; bestI[sl] = oi;
                }
            }
            if (l15 == sl) {
                unsigned long long pk =
                    ((unsigned long long)ford(bestV[sl]) << 32) | (unsigned int)bestI[sl];
                atomicMin(&packed[r0 + lk * 4 + sl], pk);
            }
        }
    }
}

__device__ void phase_codes(const unsigned long long* __restrict__ packed,
                            int* __restrict__ codes, float* __restrict__ counts) {
    const int gt = blockIdx.x * 256 + threadIdx.x, gs = gridDim.x * 256;
    for (int n = gt; n < NROWS; n += gs) {
        int c = (int)(unsigned int)(packed[n] & 0xFFFFFFFFull);
        codes[n] = c;
        atomicAdd(&counts[c], 1.0f);
    }
}

// one block of 256 threads: scan counts -> offs/cursor; usage EMA
__device__ void phase_scan(const float* __restrict__ counts, const float* __restrict__ usage,
                           int* __restrict__ offs, int* __restrict__ cursor,
                           float* __restrict__ dout, char* smbuf) {
    const int t = threadIdx.x, lane = t & 63, wid = t >> 6;
    int c4[4];
    #pragma unroll
    for (int j = 0; j < 4; j++) c4[j] = (int)counts[t * 4 + j];
    int s = c4[0] + c4[1] + c4[2] + c4[3];
    int v = s;
    #pragma unroll
    for (int off = 1; off < 64; off <<= 1) {
        int tt = __shfl_up(v, off, 64);
        if (lane >= off) v += tt;
    }
    int* ip = (int*)smbuf;
    if (lane == 63) ip[wid] = v;
    __syncthreads();
    int base = 0;
    for (int w = 0; w < wid; w++) base += ip[w];
    int run = base + v - s;
    #pragma unroll
    for (int j = 0; j < 4; j++) {
        int i = t * 4 + j;
        offs[i] = run; cursor[i] = run;
        dout[OFF_USAGE + i] = EMA_W * usage[i] + (1.0f - EMA_W) * counts[i];
        run += c4[j];
    }
    if (t == 255) offs[TS] = run;
}

__device__ void phase_epi(const float* __restrict__ x, const float* __restrict__ emb,
                          const int* __restrict__ codes, float* __restrict__ dout,
                          float* __restrict__ diffacc, int start, int stride) {
    const float4* x4p = (const float4*)x;
    const float4* e4p = (const float4*)emb;
    float4* out4 = (float4*)(dout + OFF_Q);
    float local = 0.f;
    for (int idx = start; idx < 262144; idx += stride) {
        const int row4 = idx >> 9, t4 = idx & 511;
        const int b = row4 >> 5, d0q = row4 & 31;
        const int nb2 = b * TT + t4 * 4;
        const int4 c4 = *(const int4*)(codes + nb2);
        const float4 q0 = e4p[(size_t)c4.x * 32 + d0q];
        const float4 q1 = e4p[(size_t)c4.y * 32 + d0q];
        const float4 q2 = e4p[(size_t)c4.z * 32 + d0q];
        const float4 q3 = e4p[(size_t)c4.w * 32 + d0q];
#define EPI_STEP(J, C0, C1, C2, C3) { \
        size_t plane = ((size_t)b * TD + d0q * 4 + J) * 512 + t4; \
        float4 xv = x4p[plane]; \
        float4 q = make_float4(C0, C1, C2, C3); \
        out4[plane] = q; \
        float dx = xv.x - q.x; local = fmaf(dx, dx, local); \
        dx = xv.y - q.y; local = fmaf(dx, dx, local); \
        dx = xv.z - q.z; local = fmaf(dx, dx, local); \
        dx = xv.w - q.w; local = fmaf(dx, dx, local); }
        EPI_STEP(0, q0.x, q1.x, q2.x, q3.x)
        EPI_STEP(1, q0.y, q1.y, q2.y, q3.y)
        EPI_STEP(2, q0.z, q1.z, q2.z, q3.z)
        EPI_STEP(3, q0.w, q1.w, q2.w, q3.w)
#undef EPI_STEP
    }
    #pragma unroll
    for (int off = 32; off; off >>= 1) local += __shfl_down(local, off, 64);
    if ((threadIdx.x & 63) == 0)
        atomicAdd(&diffacc[(blockIdx.x * 4 + (threadIdx.x >> 6)) & 63], local);
}

__device__ void phase_scatter(const int* __restrict__ codes, int* __restrict__ cursor,
                              int* __restrict__ rowlist) {
    const int gt = blockIdx.x * 256 + threadIdx.x, gs = gridDim.x * 256;
    for (int n = gt; n < NROWS; n += gs) {
        int pos = atomicAdd(&cursor[codes[n]], 1);
        rowlist[pos] = n;
    }
}

// unit = (code, quarter): 4096 units; 256 thr = 2 row-groups x 128 dims; atomic part acc
__device__ void phase_sum2(const _Float16* __restrict__ xhi, const _Float16* __restrict__ xlo,
                           const int* __restrict__ offs, const int* __restrict__ rowlist,
                           float* __restrict__ part, char* smbuf) {
    float* red = (float*)smbuf;
    const int tid = threadIdx.x;
    const int g = tid >> 7, d = tid & 127;
    for (int un = blockIdx.x; un < TS * 4; un += gridDim.x) {
        const int s = un >> 2, sp = un & 3;
        const int beg = offs[s], end = offs[s + 1];
        float a0 = 0.f, a1 = 0.f;
        int i = beg + sp * 2 + g;
        for (; i + 8 < end; i += 16) {
            int n0 = rowlist[i], n1 = rowlist[i + 8];
            a0 += (float)xhi[(size_t)n0 * TD + d] + (float)xlo[(size_t)n0 * TD + d];
            a1 += (float)xhi[(size_t)n1 * TD + d] + (float)xlo[(size_t)n1 * TD + d];
        }
        if (i < end) {
            int n0 = rowlist[i];
            a0 += (float)xhi[(size_t)n0 * TD + d] + (float)xlo[(size_t)n0 * TD + d];
        }
        red[tid] = a0 + a1;
        __syncthreads();
        if (tid < 128) {
            float p = red[tid] + red[tid + 128];
            if (p != 0.f) atomicAdd(&part[(size_t)s * TD + tid], p);
        }
        __syncthreads();
    }
}

__device__ void phase_fin(const float* __restrict__ emb, const float* __restrict__ counts,
                          const float* __restrict__ part, const float* __restrict__ diffacc,
                          float* __restrict__ dout) {
    const int gt = blockIdx.x * 256 + threadIdx.x, gs = gridDim.x * 256;
    for (int g = gt; g < TS * TD; g += gs) {
        int s = g >> 7;
        float cnt = counts[s];
        float e = emb[g];
        float sum = part[g];
        float tgt = (cnt > 0.f) ? (sum / cnt) : e;
        dout[OFF_EMB + g] = EMA_W * e + (1.0f - EMA_W) * tgt;
    }
    if (blockIdx.x == 0 && threadIdx.x < 64) {
        float v = diffacc[threadIdx.x];
        #pragma unroll
        for (int off = 32; off; off >>= 1) v += __shfl_down(v, off, 64);
        if (threadIdx.x == 0)
            dout[OFF_DIFF] = v * (1.0f / ((float)NROWS * (float)TD));
    }
}

// ================= the cooperative mega-kernel =================
__launch_bounds__(256, 2)
__global__ void vq_mega(const float* x, const float* emb, const float* usage, float* dout,
                        float* e2, float* counts, int* codes, int* rowlist, int* offs,
                        int* cursor, float* diffacc, unsigned long long* packed,
                        _Float16* ehi, _Float16* elo, float* part,
                        _Float16* xhi, _Float16* xlo) {
    cg::grid_group grid = cg::this_grid();
    __shared__ __align__(16) char smbuf[33792];

    phase_prep(x, emb, xhi, xlo, ehi, elo, e2, part, counts, diffacc, packed, smbuf);
    grid.sync();
    phase_dist(xhi, xlo, ehi, elo, e2, packed);
    grid.sync();
    phase_codes(packed, codes, counts);
    grid.sync();
    if (blockIdx.x == 0)
        phase_scan(counts, usage, offs, cursor, dout, smbuf);
    else
        phase_epi(x, emb, codes, dout, diffacc,
                  (blockIdx.x - 1) * 256 + threadIdx.x, (gridDim.x - 1) * 256);
    grid.sync();
    phase_scatter(codes, cursor, rowlist);
    grid.sync();
    phase_sum2(xhi, xlo, offs, rowlist, part, smbuf);
    grid.sync();
    phase_fin(emb, counts, part, diffacc, dout);
}

// ================= fallback standalone kernels =================
__global__ void vq_prep_k(const float* x, const float* emb, _Float16* xhi, _Float16* xlo,
                          _Float16* ehi, _Float16* elo, float* e2, float* part,
                          float* counts, float* diffacc, unsigned long long* packed) {
    __shared__ __align__(16) char smbuf[33792];
    phase_prep(x, emb, xhi, xlo, ehi, elo, e2, part, counts, diffacc, packed, smbuf);
}
__launch_bounds__(256, 2)
__global__ void vq_dist_k(const _Float16* xhi, const _Float16* xlo, const _Float16* ehi,
                          const _Float16* elo, const float* e2, unsigned long long* packed) {
    phase_dist(xhi, xlo, ehi, elo, e2, packed);
}
__global__ void vq_codes_k(const unsigned long long* packed, int* codes, float* counts) {
    phase_codes(packed, codes, counts);
}
__global__ void vq_scan_k(const float* counts, const float* usage, int* offs, int* cursor,
                          float* dout) {
    __shared__ __align__(16) char smbuf[64];
    phase_scan(counts, usage, offs, cursor, dout, smbuf);
}
__global__ void vq_epi_k(const float* x, const float* emb, const int* codes, float* dout,
                         float* diffacc) {
    phase_epi(x, emb, codes, dout, diffacc,
              blockIdx.x * 256 + threadIdx.x, gridDim.x * 256);
}
__global__ void vq_scatter_k(const int* codes, int* cursor, int* rowlist) {
    phase_scatter(codes, cursor, rowlist);
}
__global__ void vq_sum2_k(const _Float16* xhi, const _Float16* xlo, const int* offs,
                          const int* rowlist, float* part) {
    __shared__ __align__(16) char smbuf[1024];
    phase_sum2(xhi, xlo, offs, rowlist, part, smbuf);
}
__global__ void vq_fin_k(const float* emb, const float* counts, const float* part,
                         const float* diffacc, float* dout) {
    phase_fin(emb, counts, part, diffacc, dout);
}

extern "C" void kernel_launch(void* const* d_in, const int* in_sizes, int n_in,
                              void* d_out, int out_size, void* d_ws, size_t ws_size,
                              hipStream_t stream) {
    const float* x     = (const float*)d_in[0];
    const float* emb   = (const float*)d_in[1];
    const float* usage = (const float*)d_in[2];
    float* dout = (float*)d_out;

    float* wsf = (float*)d_ws;
    int*   wsi = (int*)d_ws;
    float* e2      = wsf + WS_E2;
    float* counts  = wsf + WS_COUNTS;
    int*   codes   = wsi + WS_CODES;
    int*   rowlist = wsi + WS_ROWLIST;
    int*   offs    = wsi + WS_OFFS;
    int*   cursor  = wsi + WS_CURSOR;
    float* diffacc = wsf + WS_DIFFACC;
    unsigned long long* packed = (unsigned long long*)(wsf + WS_PACKED);
    _Float16* ehi  = (_Float16*)(wsf + WS_EHI);
    _Float16* elo  = (_Float16*)(wsf + WS_ELO);
    float* part    = wsf + WS_PART;
    _Float16* xhi  = (_Float16*)(wsf + WS_XHI);
    _Float16* xlo  = (_Float16*)(wsf + WS_XLO);

    int nb = 0;
    hipError_t oerr = hipOccupancyMaxActiveBlocksPerMultiprocessor(&nb, vq_mega, 256, 0);
    if (oerr != hipSuccess || nb < 1) nb = 1;
    if (nb > 4) nb = 4;
    int G = nb * 256;   // co-resident by construction (256 CUs)

    void* args[] = { (void*)&x, (void*)&emb, (void*)&usage, (void*)&dout,
                     (void*)&e2, (void*)&counts, (void*)&codes, (void*)&rowlist,
                     (void*)&offs, (void*)&cursor, (void*)&diffacc, (void*)&packed,
                     (void*)&ehi, (void*)&elo, (void*)&part, (void*)&xhi, (void*)&xlo };
    hipError_t lerr = hipLaunchCooperativeKernel(vq_mega, dim3(G), dim3(256), args, 0, stream);
    if (lerr != hipSuccess) {
        // fallback: same phases as regular launches
        vq_prep_k<<<1024, 256, 0, stream>>>(x, emb, xhi, xlo, ehi, elo, e2, part,
                                            counts, diffacc, packed);
        vq_dist_k<<<1024, 256, 0, stream>>>(xhi, xlo, ehi, elo, e2, packed);
        vq_codes_k<<<NROWS / 256, 256, 0, stream>>>(packed, codes, counts);
        vq_scan_k<<<1, 256, 0, stream>>>(counts, usage, offs, cursor, dout);
        vq_epi_k<<<1024, 256, 0, stream>>>(x, emb, codes, dout, diffacc);
        vq_scatter_k<<<NROWS / 256, 256, 0, stream>>>(codes, cursor, rowlist);
        vq_sum2_k<<<2048, 256, 0, stream>>>(xhi, xlo, offs, rowlist, part);
        vq_fin_k<<<512, 256, 0, stream>>>(emb, counts, part, diffacc, dout);
    }
}

// Round 9
// 188.159 us; speedup vs baseline: 2.9743x; 2.9743x over previous
//
#include <hip/hip_runtime.h>

// Problem constants
#define TD 128        // D
#define TS 1024       // SIZE
#define TT 2048       // T
#define NROWS 32768   // B*T
#define EMA_W 0.99f

// d_out layout (flat fp32): [quantized BxDxT][diff][new_embedding SxD][new_usage S]
#define OFF_Q     0
#define OFF_DIFF  4194304
#define OFF_EMB   4194305
#define OFF_USAGE 4325377

// ws layout (words). End = 4,591,684 w = 18.37 MB < 19.15 MB (R7-proven bound)
#define WS_E2      0         // 1024 f
#define WS_COUNTS  1024      // 1024 f
#define WS_CODES   2048      // 32768 i
#define WS_ROWLIST 34816     // 32768 i
#define WS_OFFS    67584     // 1025 i
#define WS_CURSOR  68612     // 1024 i
#define WS_DIFFACC 69636     // 64 f
#define WS_PACKED  69700     // 32768 u64 = 65536 w (byte 278800 %8==0)
#define WS_EHI     135236    // 65536 w (byte 540944 %16==0)
#define WS_ELO     200772    // 65536 w
#define WS_PART    266308    // 131072 w
#define WS_XHI     397380    // 2097152 w (byte 1589520 %16==0)
#define WS_XLO     2494532   // 2097152 w -> end 4591684

typedef _Float16 f16x8 __attribute__((ext_vector_type(8)));
typedef _Float16 half4 __attribute__((ext_vector_type(4)));
typedef float    f32x4 __attribute__((ext_vector_type(4)));

__device__ __forceinline__ unsigned int ford(float s) {
    unsigned int u = __float_as_uint(s);
    return (u & 0x80000000u) ? ~u : (u | 0x80000000u);
}

// K1: x transpose + hi/lo split; emb split + e2; zero part/counts/diffacc; init packed
__global__ void vq_prep_k(const float* __restrict__ x, const float* __restrict__ emb,
                          _Float16* __restrict__ xhi, _Float16* __restrict__ xlo,
                          _Float16* __restrict__ ehi, _Float16* __restrict__ elo,
                          float* __restrict__ e2, float* __restrict__ part,
                          float* __restrict__ counts, float* __restrict__ diffacc,
                          unsigned long long* __restrict__ packed) {
    __shared__ float xs[64][132];
    const int tid = threadIdx.x, bid = blockIdx.x, G = gridDim.x;
    const int lane = tid & 63, wid = tid >> 6;
    // job A: x [B][D][T] -> xhi/xlo [N][D]
    if (bid < 512) {
        const int b = bid >> 5, tc = bid & 31;
        const float4* x4 = (const float4*)x;
        #pragma unroll
        for (int p = 0; p < 8; p++) {
            int idx = p * 256 + tid;
            int d = idx >> 4, t4 = idx & 15;
            float4 v = x4[((size_t)b * TD + d) * 512 + tc * 16 + t4];
            xs[t4 * 4 + 0][d] = v.x;
            xs[t4 * 4 + 1][d] = v.y;
            xs[t4 * 4 + 2][d] = v.z;
            xs[t4 * 4 + 3][d] = v.w;
        }
        __syncthreads();
        const int ld = tid & 31;
        #pragma unroll
        for (int p = 0; p < 8; p++) {
            int tl = p * 8 + (tid >> 5);
            float4 v = *(const float4*)&xs[tl][ld * 4];
            half4 h, l;
            h[0] = (_Float16)v.x; l[0] = (_Float16)(v.x - (float)h[0]);
            h[1] = (_Float16)v.y; l[1] = (_Float16)(v.y - (float)h[1]);
            h[2] = (_Float16)v.z; l[2] = (_Float16)(v.z - (float)h[2]);
            h[3] = (_Float16)v.w; l[3] = (_Float16)(v.w - (float)h[3]);
            size_t n = (size_t)b * TT + tc * 64 + tl;
            *(half4*)(xhi + n * TD + ld * 4) = h;
            *(half4*)(xlo + n * TD + ld * 4) = l;
        }
    }
    // job B: emb split + e2 + part zero (one wave per code row)
    {
        const int gw = bid * 4 + wid, nw = G * 4;
        for (int s = gw; s < TS; s += nw) {
            size_t base = (size_t)s * TD;
            float v0 = emb[base + lane], v1 = emb[base + 64 + lane];
            _Float16 h0 = (_Float16)v0, h1 = (_Float16)v1;
            ehi[base + lane] = h0;      elo[base + lane] = (_Float16)(v0 - (float)h0);
            ehi[base + 64 + lane] = h1; elo[base + 64 + lane] = (_Float16)(v1 - (float)h1);
            part[base + lane] = 0.f;    part[base + 64 + lane] = 0.f;
            float sq = v0 * v0 + v1 * v1;
            #pragma unroll
            for (int off = 32; off; off >>= 1) sq += __shfl_down(sq, off, 64);
            if (lane == 0) e2[s] = sq;
        }
    }
    // job C: init packed / zero counts / diffacc
    const int gt = bid * 256 + tid, gs = G * 256;
    for (int i = gt; i < NROWS; i += gs) packed[i] = ~0ull;
    for (int i = gt; i < TS; i += gs) counts[i] = 0.f;
    if (gt < 64) diffacc[gt] = 0.f;
}

// K2: distances + argmin. R6-verified body (fr=2), 4-way code split, 1024 blocks.
// 16x16x32 MFMA; 3-term hi/lo; packed u64 atomicMin merge.
__launch_bounds__(256, 2)
__global__ void vq_dist_k(const _Float16* __restrict__ xhi, const _Float16* __restrict__ xlo,
                          const _Float16* __restrict__ ehi, const _Float16* __restrict__ elo,
                          const float* __restrict__ e2,
                          unsigned long long* __restrict__ packed) {
    const int tid  = threadIdx.x;
    const int lane = tid & 63;
    const int wid  = tid >> 6;
    const int l15  = lane & 15;
    const int lk   = lane >> 4;
    const int split = blockIdx.x & 3;
    const int n0    = (blockIdx.x >> 2) * 128;
    const int cbase = split * 256;
    const int nrow  = n0 + wid * 32;

    // A frags (verified map): row = lane&15, k = (lane>>4)*8 + j
    f16x8 ahi[2][4], alo[2][4];
    #pragma unroll
    for (int fr = 0; fr < 2; fr++) {
        const size_t arow = (size_t)(nrow + fr * 16 + l15);
        #pragma unroll
        for (int ks = 0; ks < 4; ks++) {
            const size_t off = arow * TD + ks * 32 + lk * 8;
            ahi[fr][ks] = *(const f16x8*)(xhi + off);
            alo[fr][ks] = *(const f16x8*)(xlo + off);
        }
    }

    float bestV[8]; int bestI[8];
    #pragma unroll
    for (int i = 0; i < 8; i++) { bestV[i] = 3.4e38f; bestI[i] = 0; }

    #pragma unroll
    for (int tl = 0; tl < 4; ++tl) {
        const int c0 = cbase + tl * 64;
        f32x4 acc[2][4];
        #pragma unroll
        for (int fr = 0; fr < 2; fr++)
            #pragma unroll
            for (int fc = 0; fc < 4; fc++)
                acc[fr][fc] = (f32x4){0.f, 0.f, 0.f, 0.f};

        #pragma unroll
        for (int ks = 0; ks < 4; ks++) {
            f16x8 bh[4], bl[4];
            #pragma unroll
            for (int fc = 0; fc < 4; fc++) {
                const size_t off = (size_t)(c0 + fc * 16 + l15) * TD + ks * 32 + lk * 8;
                bh[fc] = *(const f16x8*)(ehi + off);
                bl[fc] = *(const f16x8*)(elo + off);
            }
            #pragma unroll
            for (int fc = 0; fc < 4; fc++)
                #pragma unroll
                for (int fr = 0; fr < 2; fr++) {
                    acc[fr][fc] = __builtin_amdgcn_mfma_f32_16x16x32_f16(ahi[fr][ks], bh[fc], acc[fr][fc], 0, 0, 0);
                    acc[fr][fc] = __builtin_amdgcn_mfma_f32_16x16x32_f16(ahi[fr][ks], bl[fc], acc[fr][fc], 0, 0, 0);
                    acc[fr][fc] = __builtin_amdgcn_mfma_f32_16x16x32_f16(alo[fr][ks], bh[fc], acc[fr][fc], 0, 0, 0);
                }
        }

        float e2v[4];
        #pragma unroll
        for (int fc = 0; fc < 4; fc++) e2v[fc] = e2[c0 + fc * 16 + l15];
        #pragma unroll
        for (int fr = 0; fr < 2; fr++)
            #pragma unroll
            for (int i = 0; i < 4; i++)
                #pragma unroll
                for (int fc = 0; fc < 4; fc++) {
                    float sc = fmaf(-2.f, acc[fr][fc][i], e2v[fc]);
                    const int slot = fr * 4 + i;
                    if (sc < bestV[slot]) { bestV[slot] = sc; bestI[slot] = c0 + fc * 16 + l15; }
                }
    }

    // argmin across the 16 lanes of each lk-group
    #pragma unroll
    for (int sl = 0; sl < 8; sl++) {
        #pragma unroll
        for (int m = 8; m >= 1; m >>= 1) {
            float ov = __shfl_xor(bestV[sl], m, 64);
            int   oi = __shfl_xor(bestI[sl], m, 64);
            if (ov < bestV[sl] || (ov == bestV[sl] && oi < bestI[sl])) {
                bestV[sl] = ov; bestI[sl] = oi;
            }
        }
    }
    // slot (fr,i) holds row nrow + fr*16 + lk*4 + i; lane l15==fr*4+i publishes
    #pragma unroll
    for (int fr = 0; fr < 2; fr++)
        #pragma unroll
        for (int i = 0; i < 4; i++)
            if (l15 == fr * 4 + i) {
                const int r = nrow + fr * 16 + lk * 4 + i;
                unsigned long long pk =
                    ((unsigned long long)ford(bestV[fr * 4 + i]) << 32)
                    | (unsigned int)bestI[fr * 4 + i];
                atomicMin(&packed[r], pk);
            }
}

// K3: epilogue fused with code extraction + counts.
// unit = (b, d-quad, t4); d0q==0 threads also write codes + counts.
__global__ void vq_epi_k(const float* __restrict__ x, const float* __restrict__ emb,
                         const unsigned long long* __restrict__ packed,
                         int* __restrict__ codes, float* __restrict__ counts,
                         float* __restrict__ dout, float* __restrict__ diffacc) {
    const int idx  = blockIdx.x * 256 + threadIdx.x;  // 0..262143
    const int row4 = idx >> 9;
    const int t4   = idx & 511;
    const int b    = row4 >> 5;
    const int d0q  = row4 & 31;
    const int nb   = b * TT + t4 * 4;
    int c[4];
    #pragma unroll
    for (int j = 0; j < 4; j++) c[j] = (int)(unsigned int)(packed[nb + j] & 0xFFFFFFFFull);
    if (d0q == 0) {
        *(int4*)(codes + nb) = make_int4(c[0], c[1], c[2], c[3]);
        #pragma unroll
        for (int j = 0; j < 4; j++) atomicAdd(&counts[c[j]], 1.0f);
    }
    const float4* x4p = (const float4*)x;
    const float4* e4p = (const float4*)emb;
    float4* out4 = (float4*)(dout + OFF_Q);
    const float4 q0 = e4p[(size_t)c[0] * 32 + d0q];
    const float4 q1 = e4p[(size_t)c[1] * 32 + d0q];
    const float4 q2 = e4p[(size_t)c[2] * 32 + d0q];
    const float4 q3 = e4p[(size_t)c[3] * 32 + d0q];
    float local = 0.f;
#define EPI_STEP(J, C0, C1, C2, C3) { \
        size_t plane = ((size_t)b * TD + d0q * 4 + J) * 512 + t4; \
        float4 xv = x4p[plane]; \
        float4 q = make_float4(C0, C1, C2, C3); \
        out4[plane] = q; \
        float dx = xv.x - q.x; local = fmaf(dx, dx, local); \
        dx = xv.y - q.y; local = fmaf(dx, dx, local); \
        dx = xv.z - q.z; local = fmaf(dx, dx, local); \
        dx = xv.w - q.w; local = fmaf(dx, dx, local); }
    EPI_STEP(0, q0.x, q1.x, q2.x, q3.x)
    EPI_STEP(1, q0.y, q1.y, q2.y, q3.y)
    EPI_STEP(2, q0.z, q1.z, q2.z, q3.z)
    EPI_STEP(3, q0.w, q1.w, q2.w, q3.w)
#undef EPI_STEP
    #pragma unroll
    for (int off = 32; off; off >>= 1) local += __shfl_down(local, off, 64);
    if ((threadIdx.x & 63) == 0)
        atomicAdd(&diffacc[(blockIdx.x * 4 + (threadIdx.x >> 6)) & 63], local);
}

// K4: one block of 256 threads: scan counts -> offs/cursor; usage EMA
__global__ void vq_scan_k(const float* __restrict__ counts, const float* __restrict__ usage,
                          int* __restrict__ offs, int* __restrict__ cursor,
                          float* __restrict__ dout) {
    __shared__ int ip[4];
    const int t = threadIdx.x, lane = t & 63, wid = t >> 6;
    int c4[4];
    #pragma unroll
    for (int j = 0; j < 4; j++) c4[j] = (int)counts[t * 4 + j];
    int s = c4[0] + c4[1] + c4[2] + c4[3];
    int v = s;
    #pragma unroll
    for (int off = 1; off < 64; off <<= 1) {
        int tt = __shfl_up(v, off, 64);
        if (lane >= off) v += tt;
    }
    if (lane == 63) ip[wid] = v;
    __syncthreads();
    int base = 0;
    for (int w = 0; w < wid; w++) base += ip[w];
    int run = base + v - s;
    #pragma unroll
    for (int j = 0; j < 4; j++) {
        int i = t * 4 + j;
        offs[i] = run; cursor[i] = run;
        dout[OFF_USAGE + i] = EMA_W * usage[i] + (1.0f - EMA_W) * counts[i];
        run += c4[j];
    }
    if (t == 255) offs[TS] = run;
}

// K5: scatter row indices into per-code segments
__global__ void vq_scatter_k(const int* __restrict__ codes, int* __restrict__ cursor,
                             int* __restrict__ rowlist) {
    int n = blockIdx.x * 256 + threadIdx.x;
    int pos = atomicAdd(&cursor[codes[n]], 1);
    rowlist[pos] = n;
}

// K6: gather-sum; unit = (code, quarter) = 4096 blocks; 256 thr = 2 row-groups x 128 dims
__global__ void vq_sum2_k(const _Float16* __restrict__ xhi, const _Float16* __restrict__ xlo,
                          const int* __restrict__ offs, const int* __restrict__ rowlist,
                          float* __restrict__ part) {
    __shared__ float red[256];
    const int tid = threadIdx.x;
    const int g = tid >> 7, d = tid & 127;
    const int s = blockIdx.x >> 2, sp = blockIdx.x & 3;
    const int beg = offs[s], end = offs[s + 1];
    float a0 = 0.f, a1 = 0.f;
    int i = beg + sp * 2 + g;
    for (; i + 8 < end; i += 16) {
        int n0 = rowlist[i], n1 = rowlist[i + 8];
        a0 += (float)xhi[(size_t)n0 * TD + d] + (float)xlo[(size_t)n0 * TD + d];
        a1 += (float)xhi[(size_t)n1 * TD + d] + (float)xlo[(size_t)n1 * TD + d];
    }
    if (i < end) {
        int n0 = rowlist[i];
        a0 += (float)xhi[(size_t)n0 * TD + d] + (float)xlo[(size_t)n0 * TD + d];
    }
    red[tid] = a0 + a1;
    __syncthreads();
    if (tid < 128) {
        float p = red[tid] + red[tid + 128];
        if (p != 0.f) atomicAdd(&part[(size_t)s * TD + tid], p);
    }
}

// K7: part -> EMA embedding; diff scalar
__global__ void vq_fin_k(const float* __restrict__ emb, const float* __restrict__ counts,
                         const float* __restrict__ part, const float* __restrict__ diffacc,
                         float* __restrict__ dout) {
    int g = blockIdx.x * 256 + threadIdx.x;  // 0..131071
    int s = g >> 7;
    float cnt = counts[s];
    float e = emb[g];
    float sum = part[g];
    float tgt = (cnt > 0.f) ? (sum / cnt) : e;
    dout[OFF_EMB + g] = EMA_W * e + (1.0f - EMA_W) * tgt;
    if (blockIdx.x == 0 && threadIdx.x < 64) {
        float v = diffacc[threadIdx.x];
        #pragma unroll
        for (int off = 32; off; off >>= 1) v += __shfl_down(v, off, 64);
        if (threadIdx.x == 0)
            dout[OFF_DIFF] = v * (1.0f / ((float)NROWS * (float)TD));
    }
}

extern "C" void kernel_launch(void* const* d_in, const int* in_sizes, int n_in,
                              void* d_out, int out_size, void* d_ws, size_t ws_size,
                              hipStream_t stream) {
    const float* x     = (const float*)d_in[0];
    const float* emb   = (const float*)d_in[1];
    const float* usage = (const float*)d_in[2];
    float* dout = (float*)d_out;

    float* wsf = (float*)d_ws;
    int*   wsi = (int*)d_ws;
    float* e2      = wsf + WS_E2;
    float* counts  = wsf + WS_COUNTS;
    int*   codes   = wsi + WS_CODES;
    int*   rowlist = wsi + WS_ROWLIST;
    int*   offs    = wsi + WS_OFFS;
    int*   cursor  = wsi + WS_CURSOR;
    float* diffacc = wsf + WS_DIFFACC;
    unsigned long long* packed = (unsigned long long*)(wsf + WS_PACKED);
    _Float16* ehi  = (_Float16*)(wsf + WS_EHI);
    _Float16* elo  = (_Float16*)(wsf + WS_ELO);
    float* part    = wsf + WS_PART;
    _Float16* xhi  = (_Float16*)(wsf + WS_XHI);
    _Float16* xlo  = (_Float16*)(wsf + WS_XLO);

    vq_prep_k<<<1024, 256, 0, stream>>>(x, emb, xhi, xlo, ehi, elo, e2, part,
                                        counts, diffacc, packed);
    vq_dist_k<<<1024, 256, 0, stream>>>(xhi, xlo, ehi, elo, e2, packed);
    vq_epi_k<<<1024, 256, 0, stream>>>(x, emb, packed, codes, counts, dout, diffacc);
    vq_scan_k<<<1, 256, 0, stream>>>(counts, usage, offs, cursor, dout);
    vq_scatter_k<<<NROWS / 256, 256, 0, stream>>>(codes, cursor, rowlist);
    vq_sum2_k<<<TS * 4, 256, 0, stream>>>(xhi, xlo, offs, rowlist, part);
    vq_fin_k<<<512, 256, 0, stream>>>(emb, counts, part, diffacc, dout);
}